// Round 1
// baseline (270.849 us; speedup 1.0000x reference)
//
#include <hip/hip_runtime.h>
#include <cstdint>
#include <cstddef>

// Problem constants (fixed by reference setup_inputs)
#define HW_      65536     // 256*256
#define NB       8         // batch
#define NC       8         // colour dim
#define NF       64        // feature dim
#define NK       8         // K_STEPS
#define NCHUNK   64        // blocks per batch in step/init kernels (1024 px each)
#define NTHREADS 256       // threads per block; 4 pixels per thread

// d_out layout (floats):
//   log_m_k : (NK+1)*NB*HW_ = 4,718,592
//   log_s_k : (NK+1)*NB*HW_ = 4,718,592
//   colour  : NB*NC*HW_     = 4,194,304
//   seeds   : NK*NB*NC      = 512
#define LMK_SZ ((size_t)(NK + 1) * NB * HW_)
#define COL_SZ ((size_t)NB * NC * HW_)

// ---------------------------------------------------------------------------
// Kernel 1: colour = einsum('bfhw,cf->bchw', features, W) + b
// ---------------------------------------------------------------------------
__global__ __launch_bounds__(NTHREADS)
void colour_kernel(const float* __restrict__ feat, const float* __restrict__ Wm,
                   const float* __restrict__ bias, float* __restrict__ colour) {
    __shared__ float sW[NC * NF];
    __shared__ float sB[NC];
    int tid = threadIdx.x;
    for (int i = tid; i < NC * NF; i += NTHREADS) sW[i] = Wm[i];
    if (tid < NC) sB[tid] = bias[tid];
    __syncthreads();

    int b   = blockIdx.y;
    int hw0 = blockIdx.x * (NTHREADS * 4) + tid * 4;
    const float* fb = feat + (size_t)b * NF * HW_ + hw0;

    float4 acc[NC];
#pragma unroll
    for (int c = 0; c < NC; ++c) acc[c] = make_float4(0.f, 0.f, 0.f, 0.f);

    for (int f = 0; f < NF; ++f) {
        float4 v = *reinterpret_cast<const float4*>(fb + (size_t)f * HW_);
#pragma unroll
        for (int c = 0; c < NC; ++c) {
            float w = sW[c * NF + f];
            acc[c].x = fmaf(v.x, w, acc[c].x);
            acc[c].y = fmaf(v.y, w, acc[c].y);
            acc[c].z = fmaf(v.z, w, acc[c].z);
            acc[c].w = fmaf(v.w, w, acc[c].w);
        }
    }

    float* cb = colour + (size_t)b * NC * HW_ + hw0;
#pragma unroll
    for (int c = 0; c < NC; ++c) {
        float4 o = acc[c];
        float bc = sB[c];
        o.x += bc; o.y += bc; o.z += bc; o.w += bc;
        *reinterpret_cast<float4*>(cb + (size_t)c * HW_) = o;
    }
}

// ---------------------------------------------------------------------------
// Kernel 2: per-chunk argmax partials for step 0 (scope == 1 -> p = rand)
// ---------------------------------------------------------------------------
__global__ __launch_bounds__(NTHREADS)
void init_argmax_kernel(const float* __restrict__ rand_pix,
                        float* __restrict__ pv, int* __restrict__ pi) {
    int b = blockIdx.y, chunk = blockIdx.x, tid = threadIdx.x;
    int hw0 = chunk * (NTHREADS * 4) + tid * 4;

    float4 r = *reinterpret_cast<const float4*>(rand_pix + (size_t)b * HW_ + hw0);
    float bv = r.x; int bi = hw0;
    if (r.y > bv) { bv = r.y; bi = hw0 + 1; }
    if (r.z > bv) { bv = r.z; bi = hw0 + 2; }
    if (r.w > bv) { bv = r.w; bi = hw0 + 3; }

    __shared__ float sv[NTHREADS];
    __shared__ int   si[NTHREADS];
    sv[tid] = bv; si[tid] = bi;
    __syncthreads();
    for (int s = NTHREADS / 2; s > 0; s >>= 1) {
        if (tid < s) {
            float ov = sv[tid + s]; int oi = si[tid + s];
            if (ov > sv[tid] || (ov == sv[tid] && oi < si[tid])) { sv[tid] = ov; si[tid] = oi; }
        }
        __syncthreads();
    }
    if (tid == 0) { pv[b * NCHUNK + chunk] = sv[0]; pi[b * NCHUNK + chunk] = si[0]; }
}

// ---------------------------------------------------------------------------
// Kernel 3: one scan step.
//  stage 1: reduce prev partials -> idx; gather seed; (chunk 0) write seeds out
//  stage 2: dist/alpha/log_m/log_s updates for 1024 pixels
//  stage 3: per-chunk argmax partial for the NEXT step from log_s_new
// ---------------------------------------------------------------------------
__global__ __launch_bounds__(NTHREADS)
void step_kernel(const float* __restrict__ colour, const float* __restrict__ rand_pix,
                 const float* __restrict__ log_sigma_p,
                 float* __restrict__ log_m_k, float* __restrict__ log_s_k,
                 float* __restrict__ seeds,
                 const float* __restrict__ pv_in, const int* __restrict__ pi_in,
                 float* __restrict__ pv_out, int* __restrict__ pi_out,
                 int k) {
    int b = blockIdx.y, chunk = blockIdx.x, tid = threadIdx.x;

    __shared__ float sv[NTHREADS];
    __shared__ int   si[NTHREADS];
    __shared__ float sSeed[NC];
    __shared__ float sSigma;

    // ---- stage 1: reduce NCHUNK partials for this batch ----
    if (tid < NCHUNK) { sv[tid] = pv_in[b * NCHUNK + tid]; si[tid] = pi_in[b * NCHUNK + tid]; }
    __syncthreads();
    for (int s = NCHUNK / 2; s > 0; s >>= 1) {
        if (tid < s) {
            float ov = sv[tid + s]; int oi = si[tid + s];
            if (ov > sv[tid] || (ov == sv[tid] && oi < si[tid])) { sv[tid] = ov; si[tid] = oi; }
        }
        __syncthreads();
    }
    int idx = si[0];
    if (tid < NC) {
        float sc = colour[((size_t)b * NC + tid) * HW_ + idx];
        sSeed[tid] = sc;
        if (chunk == 0) seeds[((size_t)k * NB + b) * NC + tid] = sc;
    }
    if (tid == 0) sSigma = expf(log_sigma_p[0]);
    __syncthreads();

    // ---- stage 2: elementwise update on 4 pixels ----
    int hw0 = chunk * (NTHREADS * 4) + tid * 4;
    size_t base = (size_t)b * HW_ + hw0;

    float4 ls;
    if (k == 0) {
        ls = make_float4(0.f, 0.f, 0.f, 0.f);
        // materialize log_s_k[0] = 0 (d_out is poisoned each call)
        *reinterpret_cast<float4*>(log_s_k + base) = ls;
    } else {
        ls = *reinterpret_cast<const float4*>(log_s_k + (size_t)k * NB * HW_ + base);
    }

    float4 dist = make_float4(0.f, 0.f, 0.f, 0.f);
    const float* cb = colour + (size_t)b * NC * HW_ + hw0;
#pragma unroll
    for (int c = 0; c < NC; ++c) {
        float4 cv = *reinterpret_cast<const float4*>(cb + (size_t)c * HW_);
        float sd = sSeed[c];
        float dx = cv.x - sd, dy = cv.y - sd, dz = cv.z - sd, dw = cv.w - sd;
        dist.x = fmaf(dx, dx, dist.x);
        dist.y = fmaf(dy, dy, dist.y);
        dist.z = fmaf(dz, dz, dist.z);
        dist.w = fmaf(dw, dw, dist.w);
    }

    float sigma = sSigma;
    float ax = expf(-dist.x / sigma), ay = expf(-dist.y / sigma);
    float az = expf(-dist.z / sigma), aw = expf(-dist.w / sigma);
    ax = fminf(fmaxf(ax, 0.01f), 0.99f);
    ay = fminf(fmaxf(ay, 0.01f), 0.99f);
    az = fminf(fmaxf(az, 0.01f), 0.99f);
    aw = fminf(fmaxf(aw, 0.01f), 0.99f);

    float4 lm = make_float4(ls.x + logf(ax), ls.y + logf(ay),
                            ls.z + logf(az), ls.w + logf(aw));
    float4 ln = make_float4(ls.x + logf(1.0f - ax), ls.y + logf(1.0f - ay),
                            ls.z + logf(1.0f - az), ls.w + logf(1.0f - aw));

    *reinterpret_cast<float4*>(log_m_k + (size_t)k * NB * HW_ + base) = lm;
    *reinterpret_cast<float4*>(log_s_k + (size_t)(k + 1) * NB * HW_ + base) = ln;
    if (k == NK - 1) {
        // log_m_k[K] = last_log_s
        *reinterpret_cast<float4*>(log_m_k + (size_t)NK * NB * HW_ + base) = ln;
    }

    // ---- stage 3: argmax partial for next step: p = rand * exp(log_s_new) ----
    float4 r = *reinterpret_cast<const float4*>(rand_pix + base);
    float px = r.x * expf(ln.x), py = r.y * expf(ln.y);
    float pz = r.z * expf(ln.z), pw = r.w * expf(ln.w);
    float bv = px; int bi = hw0;
    if (py > bv) { bv = py; bi = hw0 + 1; }
    if (pz > bv) { bv = pz; bi = hw0 + 2; }
    if (pw > bv) { bv = pw; bi = hw0 + 3; }

    __syncthreads();   // sv/si reuse
    sv[tid] = bv; si[tid] = bi;
    __syncthreads();
    for (int s = NTHREADS / 2; s > 0; s >>= 1) {
        if (tid < s) {
            float ov = sv[tid + s]; int oi = si[tid + s];
            if (ov > sv[tid] || (ov == sv[tid] && oi < si[tid])) { sv[tid] = ov; si[tid] = oi; }
        }
        __syncthreads();
    }
    if (tid == 0) { pv_out[b * NCHUNK + chunk] = sv[0]; pi_out[b * NCHUNK + chunk] = si[0]; }
}

// ---------------------------------------------------------------------------
extern "C" void kernel_launch(void* const* d_in, const int* in_sizes, int n_in,
                              void* d_out, int out_size, void* d_ws, size_t ws_size,
                              hipStream_t stream) {
    const float* feat      = (const float*)d_in[0];  // [8,64,256,256]
    const float* Wm        = (const float*)d_in[1];  // [8,64]
    const float* bias      = (const float*)d_in[2];  // [8]
    const float* log_sigma = (const float*)d_in[3];  // [1]
    const float* rand_pix  = (const float*)d_in[4];  // [8,1,256,256]
    // d_in[5] = steps_to_run (== NK, fixed)

    float* out     = (float*)d_out;
    float* log_m_k = out;                       // (NK+1)*NB*HW_
    float* log_s_k = out + LMK_SZ;              // (NK+1)*NB*HW_
    float* colour  = out + 2 * LMK_SZ;          // NB*NC*HW_
    float* seeds   = colour + COL_SZ;           // NK*NB*NC

    // workspace: double-buffered argmax partials
    float* pv = (float*)d_ws;                              // [2][NB][NCHUNK]
    int*   pi = (int*)((char*)d_ws + 2 * NB * NCHUNK * 4); // [2][NB][NCHUNK]

    dim3 grid(NCHUNK, NB);

    colour_kernel<<<grid, NTHREADS, 0, stream>>>(feat, Wm, bias, colour);
    init_argmax_kernel<<<grid, NTHREADS, 0, stream>>>(rand_pix, pv, pi);

    for (int k = 0; k < NK; ++k) {
        int cur = k & 1, nxt = (k + 1) & 1;
        step_kernel<<<grid, NTHREADS, 0, stream>>>(
            colour, rand_pix, log_sigma,
            log_m_k, log_s_k, seeds,
            pv + cur * NB * NCHUNK, pi + cur * NB * NCHUNK,
            pv + nxt * NB * NCHUNK, pi + nxt * NB * NCHUNK,
            k);
    }
}